// Round 3
// baseline (1179.251 us; speedup 1.0000x reference)
//
#include <hip/hip_runtime.h>

// NeighborSample: x[8,64,64,192] f32 -> out[8*64*64, 5, 5, 192] f32
// out[p, i, j, k] = x[b, y+i-2, x+j-2, k] (zero-padded), p = (b*64+y)*64+x
//
// R2: same as R1 but with native Clang vector type (ext_vector_type) so
// __builtin_nontemporal_store compiles. 64 B per thread (4 float4) for 4x
// MLP + 4x amortized index math; tap (i,j) in blockIdx.y; nontemporal
// stores keep the 600 MiB write stream from evicting the 24 MiB input.

typedef float f32x4 __attribute__((ext_vector_type(4)));

constexpr int B = 8;
constexpr int H = 64;
constexpr int W = 64;
constexpr int C = 192;
constexpr int C4 = C / 4;           // 48 float4 per channel row
constexpr int K = 5;
constexpr int PAD = K / 2;

constexpr int T4 = 4;               // float4 per thread (64 B)
constexpr int NT = C4 / T4;         // 12 threads per channel row
constexpr int BLOCK = 256;
constexpr unsigned NPIX = (unsigned)B * H * W;            // 32768
constexpr unsigned GRID_X = NPIX * NT / BLOCK;            // 1536 (exact)

__global__ __launch_bounds__(BLOCK) void neighbor_sample_kernel(
    const f32x4* __restrict__ in, f32x4* __restrict__ out) {
  unsigned g = blockIdx.x * BLOCK + threadIdx.x;   // p * NT + t4
  unsigned t4 = g % NT;                            // magic-mul divide
  unsigned p  = g / NT;                            // pixel index < 32768

  int pos = (int)blockIdx.y;                       // 0..24
  int i = pos / K;
  int j = pos - i * K;

  int xx = (int)(p & (W - 1));
  int yy = (int)((p >> 6) & (H - 1));
  int b  = (int)(p >> 12);

  int sy = yy + i - PAD;
  int sx = xx + j - PAD;

  unsigned k4  = t4 * T4;
  unsigned dst = p * (unsigned)(K * K * C4) + (unsigned)pos * C4 + k4;

  f32x4 v0 = (f32x4)(0.f);
  f32x4 v1 = v0, v2 = v0, v3 = v0;

  if ((unsigned)sy < (unsigned)H && (unsigned)sx < (unsigned)W) {
    unsigned src = (((unsigned)(b * H + sy) * W) + (unsigned)sx) * C4 + k4;
    // 4 independent loads issued back-to-back: 4x memory-level parallelism
    v0 = in[src + 0];
    v1 = in[src + 1];
    v2 = in[src + 2];
    v3 = in[src + 3];
  }

  // Nontemporal: write stream never re-read; don't evict the input from L2.
  __builtin_nontemporal_store(v0, &out[dst + 0]);
  __builtin_nontemporal_store(v1, &out[dst + 1]);
  __builtin_nontemporal_store(v2, &out[dst + 2]);
  __builtin_nontemporal_store(v3, &out[dst + 3]);
}

extern "C" void kernel_launch(void* const* d_in, const int* in_sizes, int n_in,
                              void* d_out, int out_size, void* d_ws, size_t ws_size,
                              hipStream_t stream) {
  const f32x4* in = (const f32x4*)d_in[0];
  f32x4* out = (f32x4*)d_out;
  dim3 grid(GRID_X, K * K, 1);
  neighbor_sample_kernel<<<grid, BLOCK, 0, stream>>>(in, out);
}

// Round 4
// 706.744 us; speedup vs baseline: 1.6686x; 1.6686x over previous
//
#include <hip/hip_runtime.h>

// NeighborSample: x[8,64,64,192] f32 -> out[8*64*64, 5, 5, 192] f32
// out[p, i, j, k] = x[b, y+i-2, x+j-2, k] (zero-padded), p = (b*64+y)*64+x
//
// R3: lessons from R2's counters: nt stores caused 2.2x HBM write
// amplification (WRITE_SIZE 614 MB -> 1.38 GB) — removed. Keep 64 B/thread
// (4 float4, row-aligned so one validity check per thread) but go back to
// R0's flat gid layout so the whole grid writes the output perfectly
// sequentially (the access pattern fillBufferAligned uses to hit 6.3 TB/s).

typedef float f32x4 __attribute__((ext_vector_type(4)));

constexpr int B = 8;
constexpr int H = 64;
constexpr int W = 64;
constexpr int C = 192;
constexpr int C4 = C / 4;           // 48 float4 per channel row
constexpr int K = 5;
constexpr int PAD = K / 2;

constexpr int T4 = 4;               // float4 per thread (64 B)
constexpr int NT = C4 / T4;         // 12 threads per channel row (48%4==0)
constexpr int BLOCK = 256;
constexpr unsigned NPIX = (unsigned)B * H * W;                  // 32768
constexpr unsigned TOTAL_THREADS = NPIX * (unsigned)(K * K) * NT;  // 9,830,400
constexpr unsigned GRID_X = TOTAL_THREADS / BLOCK;              // 38,400 exact

__global__ __launch_bounds__(BLOCK) void neighbor_sample_kernel(
    const f32x4* __restrict__ in, f32x4* __restrict__ out) {
  unsigned g = blockIdx.x * BLOCK + threadIdx.x;

  // g = (p*25 + pos)*12 + t   (magic-multiply divides, compile-time consts)
  unsigned t    = g % NT;
  unsigned rest = g / NT;            // p*25 + pos
  unsigned pos  = rest % (K * K);
  unsigned p    = rest / (K * K);

  int i = (int)(pos / K);
  int j = (int)(pos % K);

  int xx = (int)(p & (W - 1));
  int yy = (int)((p >> 6) & (H - 1));
  int b  = (int)(p >> 12);

  int sy = yy + i - PAD;
  int sx = xx + j - PAD;

  unsigned k4  = t * T4;
  unsigned dst = g * T4;             // output written perfectly sequentially

  f32x4 v0 = (f32x4)(0.f);
  f32x4 v1 = v0, v2 = v0, v3 = v0;

  if ((unsigned)sy < (unsigned)H && (unsigned)sx < (unsigned)W) {
    unsigned src = (((unsigned)(b * H + sy) * W) + (unsigned)sx) * C4 + k4;
    // 4 independent loads: 4x memory-level parallelism, served from L2/L3
    v0 = in[src + 0];
    v1 = in[src + 1];
    v2 = in[src + 2];
    v3 = in[src + 3];
  }

  // Regular write-back stores: full-line coalescing in L2, no amplification.
  out[dst + 0] = v0;
  out[dst + 1] = v1;
  out[dst + 2] = v2;
  out[dst + 3] = v3;
}

extern "C" void kernel_launch(void* const* d_in, const int* in_sizes, int n_in,
                              void* d_out, int out_size, void* d_ws, size_t ws_size,
                              hipStream_t stream) {
  const f32x4* in = (const f32x4*)d_in[0];
  f32x4* out = (f32x4*)d_out;
  neighbor_sample_kernel<<<GRID_X, BLOCK, 0, stream>>>(in, out);
}

// Round 5
// 629.649 us; speedup vs baseline: 1.8729x; 1.1224x over previous
//
#include <hip/hip_runtime.h>

// NeighborSample: x[8,64,64,192] f32 -> out[8*64*64, 5, 5, 192] f32
// R4: SCATTER formulation. R0-R3 gather read each input element 25x
// (600 MB of L2/L3 read traffic alongside the 614 MB write stream -> ~2.6
// TB/s effective). Here one thread owns one input float4 (24 MB read ONCE,
// perfectly coalesced) and stores it to the 25 output taps it feeds; all 25
// output offsets are compile-time constants off pbase. Border-pixel threads
// additionally zero-fill their own OOB taps, so every output element is
// written exactly once. Interior waves (88%) take a predicate-free path.

typedef float f32x4 __attribute__((ext_vector_type(4)));

constexpr int B = 8;
constexpr int H = 64;
constexpr int W = 64;
constexpr int C4 = 48;              // 192 ch / 4 = float4 per channel row
constexpr int K = 5;
constexpr int PAD = K / 2;
constexpr int ROW = K * K * C4;     // 1200 float4 per output pixel

constexpr unsigned NPIX  = (unsigned)B * H * W;   // 32768
constexpr unsigned TOTAL = NPIX * C4;             // 1,572,864 threads
constexpr int BLOCK = 256;
constexpr unsigned GRID = TOTAL / BLOCK;          // 6144, exact

__global__ __launch_bounds__(BLOCK) void neighbor_scatter_kernel(
    const f32x4* __restrict__ in, f32x4* __restrict__ out) {
  unsigned g  = blockIdx.x * BLOCK + threadIdx.x;  // p*48 + k4
  unsigned k4 = g % C4;                            // magic-mul
  unsigned p  = g / C4;

  int xx = (int)(p & (W - 1));
  int yy = (int)((p >> 6) & (H - 1));

  f32x4 v = in[g];                                 // coalesced, read once
  int pbase = (int)(p * (unsigned)ROW + k4);

  bool interior = (yy >= PAD) & (yy < H - PAD) & (xx >= PAD) & (xx < W - PAD);

  if (__all(interior)) {
    // All 25 targets valid; offsets are compile-time constants.
#pragma unroll
    for (int oi = 0; oi < K; ++oi)
#pragma unroll
      for (int oj = 0; oj < K; ++oj) {
        const int off = ((PAD - oi) * W + (PAD - oj)) * ROW + (oi * K + oj) * C4;
        out[pbase + off] = v;
      }
  } else {
    const f32x4 z = {0.f, 0.f, 0.f, 0.f};
#pragma unroll
    for (int oi = 0; oi < K; ++oi)
#pragma unroll
      for (int oj = 0; oj < K; ++oj) {
        const int off = ((PAD - oi) * W + (PAD - oj)) * ROW + (oi * K + oj) * C4;
        // Scatter: value v lands at tap (oi,oj) of pixel (yy+2-oi, xx+2-oj)
        int ty = yy + PAD - oi, tx = xx + PAD - oj;
        if ((unsigned)ty < (unsigned)H && (unsigned)tx < (unsigned)W)
          out[pbase + off] = v;
        // Zero-fill: own pixel's tap (oi,oj) reads OOB source -> must be 0
        int sy = yy + oi - PAD, sx = xx + oj - PAD;
        if (!((unsigned)sy < (unsigned)H && (unsigned)sx < (unsigned)W))
          out[pbase + (oi * K + oj) * C4] = z;
      }
  }
}

extern "C" void kernel_launch(void* const* d_in, const int* in_sizes, int n_in,
                              void* d_out, int out_size, void* d_ws, size_t ws_size,
                              hipStream_t stream) {
  const f32x4* in = (const f32x4*)d_in[0];
  f32x4* out = (f32x4*)d_out;
  neighbor_scatter_kernel<<<GRID, BLOCK, 0, stream>>>(in, out);
}